// Round 4
// baseline (112.158 us; speedup 1.0000x reference)
//
#include <hip/hip_runtime.h>

// ALNN layer: B=64, K=13, L=200, D=64, fp32. Two-stage, HBM-traffic-minimized.
//
// R3 lesson: partials are HBM-priced (cross-XCD consumer + ws poison), so
// minimize them: LC=4 -> partial array [NC=50][B][K][D] = 10.65 MB (was 21.3).
// Occupancy recovered via block-level k-split (Gk=2): grid = 50*8*2 = 800
// active blocks, 256 thr = dq(16) x lh(2, wave-internal) x b8(8).
// Each thread: 2 l x 7 k, acc[7] float4 (no spill); lh-fold = 1 shfl_xor(16).
// Same-c blocks (8 bg x 2 ks) all land on one XCD (bid%8 == c%8) so the
// ks=1 block's input re-read and bg weight re-reads are L2 hits.
// Stage 2: 4 threads per output float4, 13 chunks each (stride-4), 2 folds.

#define NB 64
#define NK 13
#define NL 200
#define ND 64
#define ND4 16        // float4s per d-row
#define LC 4          // l per chunk
#define NC (NL / LC)  // 50 chunks

__global__ __launch_bounds__(256) void alnn_stage1(
    const float* __restrict__ X, const float* __restrict__ T,
    const float* __restrict__ M, const float* __restrict__ DT,
    const float* __restrict__ alpha, const float* __restrict__ w_v,
    const float* __restrict__ w_t, const float* __restrict__ b_t,
    float4* __restrict__ part)
{
    // Grid 896 = 8 xcd-slots x (7 chi x 8 bg x 2 ks); c = chi*8 + clo.
    // bid%8 == c%8 -> all 16 blocks sharing chunk c's weights/inputs on one
    // XCD's L2 (round-robin dispatch heuristic; perf-only).
    const int bid = blockIdx.x;
    const int clo = bid & 7;
    const int g   = bid >> 3;          // 0..111
    const int ks  = g & 1;             // k-slot: k 0..6 / 7..12
    const int bg  = (g >> 1) & 7;      // batch group
    const int chi = g >> 4;            // 0..6
    const int c   = chi * 8 + clo;
    if (c >= NC) return;

    const int tid = threadIdx.x;
    const int dq  = tid & 15;          // float4 index along d
    const int lh  = (tid >> 4) & 1;    // l-half (wave-internal: bit 4)
    const int b8  = tid >> 5;          // 0..7
    const int k0  = ks * 7;
    const int b   = (bg << 3) + b8;
    const int la  = c * LC + (lh << 1);  // this thread's 2 l: la, la+1

    const float4* X4  = (const float4*)X;
    const float4* T4  = (const float4*)T;
    const float4* M4  = (const float4*)M;
    const float4* DT4 = (const float4*)DT;
    const float4* WT4 = (const float4*)w_t;   // f4 idx = (k*NL+l)*ND + d
    const float4* BT4 = (const float4*)b_t;   // f4 idx = (k*NL+l)*ND4 + dq
    const float4* WV4 = (const float4*)w_v;

    float av[7], rv[7];
    #pragma unroll
    for (int i = 0; i < 7; ++i) {
        const int k = k0 + i;
        av[i] = (k < NK) ? fmaxf(alpha[k], 0.f) : 0.f;
        rv[i] = 4.f * (float)k;        // linspace(0,48,13) step = 4
    }

    float4 acc[7];
    #pragma unroll
    for (int i = 0; i < 7; ++i) acc[i] = make_float4(0.f, 0.f, 0.f, 0.f);

#define COMP(c_, wt, A) {                                                 \
        const float dist  = fabsf(t4.c_ - reft);                          \
        const float inten = fmaxf(x4.c_ * __expf(-a * dist), 0.f);        \
        const float sf = wt.x * x4.c_ + wt.y * dt4.c_ + wt.z * inten +    \
                         wt.w * m4.c_ + 4.f * bt4.c_;                     \
        A.c_ = fmaf(wv4.c_, fmaxf(sf, 0.f), A.c_);                        \
    }

    #pragma unroll
    for (int li = 0; li < 2; ++li) {
        const int l  = la + li;
        const int io = (b * NL + l) * ND4 + dq;
        const float4 x4  = X4[io];
        const float4 t4  = T4[io];
        const float4 m4  = M4[io];
        const float4 dt4 = DT4[io];
        #pragma unroll
        for (int i = 0; i < 7; ++i) {
            const int k = k0 + i;
            if (k < NK) {
                const int w0 = (k * NL + l) * ND + (dq << 2);
                const float4 wt0 = WT4[w0 + 0];
                const float4 wt1 = WT4[w0 + 1];
                const float4 wt2 = WT4[w0 + 2];
                const float4 wt3 = WT4[w0 + 3];
                const int   wq  = (k * NL + l) * ND4 + dq;
                const float4 bt4 = BT4[wq];
                const float4 wv4 = WV4[wq];
                const float a    = av[i];
                const float reft = rv[i];
                COMP(x, wt0, acc[i])
                COMP(y, wt1, acc[i])
                COMP(z, wt2, acc[i])
                COMP(w, wt3, acc[i])
            }
        }
    }
#undef COMP

    // fold the two l-halves (lanes tid^16, same wave); both halves then
    // hold the full 4-l chunk sum -> split the k-stores between them
    #pragma unroll
    for (int i = 0; i < 7; ++i) {
        acc[i].x += __shfl_xor(acc[i].x, 16);
        acc[i].y += __shfl_xor(acc[i].y, 16);
        acc[i].z += __shfl_xor(acc[i].z, 16);
        acc[i].w += __shfl_xor(acc[i].w, 16);
    }

    const int pb = ((c * NB + b) * NK + k0) * ND4 + dq;
    #pragma unroll
    for (int i = 0; i < 7; ++i) {
        const int k = k0 + i;
        if (k < NK && ((i < 4) == (lh == 0)))   // lh0: i 0..3, lh1: i 4..6
            part[pb + i * ND4] = acc[i];
    }
}

__global__ __launch_bounds__(256) void alnn_stage2(
    const float4* __restrict__ part, const float* __restrict__ b_v,
    float4* __restrict__ out)
{
    // 4 threads per output float4; q handles c = q, q+4, q+8, ... (13/13/12/12).
    // g = bk*64 + q*16 + dq -> NB*NK*64 = 53248 threads = 208 blocks exactly.
    const int g  = blockIdx.x * 256 + threadIdx.x;   // 0..53247
    const int dq = g & 15;
    const int r  = g >> 4;
    const int q  = r & 3;
    const int bk = r >> 2;                           // b*NK + k, 0..831
    if (bk >= NB * NK) return;                       // defensive

    float4 s = make_float4(0.f, 0.f, 0.f, 0.f);
    #pragma unroll
    for (int i = 0; i < 13; ++i) {
        const int c = q + (i << 2);
        if (c < NC) {
            const float4 p = part[(c * NB * NK + bk) * ND4 + dq];
            s.x += p.x; s.y += p.y; s.z += p.z; s.w += p.w;
        }
    }
    // fold the 4 q-partials (lanes differ in bits 4..5 of the wave)
    s.x += __shfl_xor(s.x, 16); s.y += __shfl_xor(s.y, 16);
    s.z += __shfl_xor(s.z, 16); s.w += __shfl_xor(s.w, 16);
    s.x += __shfl_xor(s.x, 32); s.y += __shfl_xor(s.y, 32);
    s.z += __shfl_xor(s.z, 32); s.w += __shfl_xor(s.w, 32);

    if (q == 0) {
        const int k = bk % NK;
        const float4 bv = ((const float4*)b_v)[k * ND4 + dq];
        float4 o;
        o.x = fmaxf(s.x + 200.f * bv.x, 0.f);
        o.y = fmaxf(s.y + 200.f * bv.y, 0.f);
        o.z = fmaxf(s.z + 200.f * bv.z, 0.f);
        o.w = fmaxf(s.w + 200.f * bv.w, 0.f);
        out[bk * ND4 + dq] = o;
    }
}

extern "C" void kernel_launch(void* const* d_in, const int* in_sizes, int n_in,
                              void* d_out, int out_size, void* d_ws, size_t ws_size,
                              hipStream_t stream) {
    const float* X     = (const float*)d_in[0];
    const float* T     = (const float*)d_in[1];
    const float* M     = (const float*)d_in[2];
    const float* DT    = (const float*)d_in[3];
    const float* alpha = (const float*)d_in[4];
    const float* w_v   = (const float*)d_in[5];
    const float* w_t   = (const float*)d_in[6];
    const float* b_v   = (const float*)d_in[7];
    const float* b_t   = (const float*)d_in[8];

    float4* part = (float4*)d_ws;    // 10.65 MB; ws is 256 MiB

    alnn_stage1<<<896, 256, 0, stream>>>(X, T, M, DT, alpha, w_v, w_t, b_t, part);
    alnn_stage2<<<(NB * NK * 64) / 256, 256, 0, stream>>>(part, b_v, (float4*)d_out);
}

// Round 7
// 94.320 us; speedup vs baseline: 1.1891x; 1.1891x over previous
//
#include <hip/hip_runtime.h>

// ALNN layer: B=64, K=13, L=200, D=64, fp32. Single fused kernel (R0
// structure restored — every two-stage variant measured slower: partials
// are HBM-priced because the 256 MiB ws poison-fill runs every iteration
// and the stage-2 gather is cross-XCD).
//
// Change vs R0: 4 batches per block (was 2). Weights (6 float4) are loaded
// once per (k,l,dq) and reused across four batches held in transient
// registers -> weight traffic 128 MB -> 64 MB, total ~230 MB.
// Live state ~18 float4 (~105 VGPR): no spill, same 256-thread block,
// same l-split + 16 KB LDS reduce, one launch, no scratch, no atomics.
// Grid 13*16 = 208; same-bq blocks share inputs across k and co-locate on
// one XCD under round-robin dispatch (16 = 0 mod 8), as in R0.
//
// (Rounds 5+6 were infra failures — container acquisition, no kernel
// evidence; identical source resubmitted for Round 7.)

#define NB 64
#define NK 13
#define NL 200
#define ND 64

__global__ __launch_bounds__(256) void alnn_fused(
    const float* __restrict__ X, const float* __restrict__ T,
    const float* __restrict__ M, const float* __restrict__ DT,
    const float* __restrict__ alpha, const float* __restrict__ w_v,
    const float* __restrict__ w_t, const float* __restrict__ b_v,
    const float* __restrict__ b_t, float* __restrict__ out)
{
    const int k   = blockIdx.x >> 4;      // 0..12
    const int bq  = blockIdx.x & 15;      // batch quad 0..15
    const int tid = threadIdx.x;
    const int dq  = tid & 15;             // d-quad
    const int d0  = dq << 2;
    const int lsub = tid >> 4;            // 0..15

    const float a    = fmaxf(alpha[k], 0.0f);
    const float reft = 4.0f * (float)k;   // linspace(0,48,13) step = 4

    const float4* X4  = (const float4*)X;
    const float4* T4  = (const float4*)T;
    const float4* M4  = (const float4*)M;
    const float4* DT4 = (const float4*)DT;
    const float4* WT4 = (const float4*)w_t;   // [k,l,d] -> one float4 each
    const float4* BT4 = (const float4*)b_t;
    const float4* WV4 = (const float4*)w_v;

    const int b0 = bq << 2;               // 4 consecutive batches

    float4 acc0 = make_float4(0.f, 0.f, 0.f, 0.f);
    float4 acc1 = make_float4(0.f, 0.f, 0.f, 0.f);
    float4 acc2 = make_float4(0.f, 0.f, 0.f, 0.f);
    float4 acc3 = make_float4(0.f, 0.f, 0.f, 0.f);

#define COMP(c, wt, acc) {                                                \
        const float dist  = fabsf(t4.c - reft);                           \
        const float kern  = __expf(-a * dist);                            \
        const float inten = fmaxf(x4.c * kern, 0.0f);                     \
        const float sf = wt.x * x4.c + wt.y * dt4.c + wt.z * inten +      \
                         wt.w * m4.c + 4.0f * bt4.c;                      \
        acc.c = fmaf(wv4.c, fmaxf(sf, 0.0f), acc.c);                      \
    }

#define BATCH(bi, acc) {                                                  \
        const int io = (((bi) * NL + l) * ND + d0) >> 2;                  \
        const float4 x4  = X4[io];                                        \
        const float4 t4  = T4[io];                                        \
        const float4 m4  = M4[io];                                        \
        const float4 dt4 = DT4[io];                                       \
        COMP(x, wtA, acc) COMP(y, wtB, acc)                               \
        COMP(z, wtC, acc) COMP(w, wtD, acc)                               \
    }

    for (int j = 0; j < 13; ++j) {
        const int l = (j << 4) + lsub;
        if (l < NL) {
            const int wd = (k * NL + l) * ND + d0;   // flat [k,l,d] float idx
            const float4 wtA = WT4[wd + 0];
            const float4 wtB = WT4[wd + 1];
            const float4 wtC = WT4[wd + 2];
            const float4 wtD = WT4[wd + 3];
            const float4 bt4 = BT4[wd >> 2];
            const float4 wv4 = WV4[wd >> 2];
            BATCH(b0 + 0, acc0)
            BATCH(b0 + 1, acc1)
            BATCH(b0 + 2, acc2)
            BATCH(b0 + 3, acc3)
        }
    }
#undef BATCH
#undef COMP

    // LDS reduce over the 16 l-slices: red[lsub][b][dq] float4 = 16 KB
    __shared__ float4 red[16][4][16];
    red[lsub][0][dq] = acc0;
    red[lsub][1][dq] = acc1;
    red[lsub][2][dq] = acc2;
    red[lsub][3][dq] = acc3;
    __syncthreads();

    // 256 threads -> 4 batches x 64 d, one output each, 16 adds
    {
        const int b = tid >> 6;        // 0..3
        const int d = tid & 63;
        const float* redf = (const float*)red;
        // float address: ls*256 + b*64 + d (lanes d consecutive: no conflict)
        float s = 0.0f;
        #pragma unroll
        for (int ls = 0; ls < 16; ++ls)
            s += redf[ls * 256 + b * 64 + d];
        const int bi = b0 + b;
        s += (float)NL * b_v[k * ND + d];
        out[(bi * NK + k) * ND + d] = fmaxf(s, 0.0f);
    }
}

extern "C" void kernel_launch(void* const* d_in, const int* in_sizes, int n_in,
                              void* d_out, int out_size, void* d_ws, size_t ws_size,
                              hipStream_t stream) {
    const float* X     = (const float*)d_in[0];
    const float* T     = (const float*)d_in[1];
    const float* M     = (const float*)d_in[2];
    const float* DT    = (const float*)d_in[3];
    const float* alpha = (const float*)d_in[4];
    const float* w_v   = (const float*)d_in[5];
    const float* w_t   = (const float*)d_in[6];
    const float* b_v   = (const float*)d_in[7];
    const float* b_t   = (const float*)d_in[8];
    float* out = (float*)d_out;

    alnn_fused<<<NK * 16, 256, 0, stream>>>(X, T, M, DT, alpha, w_v, w_t, b_v, b_t, out);
}